// Round 4
// baseline (1508.013 us; speedup 1.0000x reference)
//
#include <hip/hip_runtime.h>
#include <hip/hip_bf16.h>

typedef __attribute__((ext_vector_type(8))) short short8;
typedef __attribute__((ext_vector_type(4))) float f32x4;
typedef __attribute__((ext_vector_type(2))) float f32x2;

constexpr int T    = 60;    // driven timesteps
constexpr int C    = 128;   // channels == hidden
constexpr int NPIX = 4096;  // samples
constexpr int H    = 128;
constexpr int GP   = 5;
constexpr int EXTRA = T - GP - 1;   // 54 autoregressive steps
constexpr int TT    = T + EXTRA;    // 114 total outputs
constexpr int SAMP  = 8;            // samples per WG (was 16) -> 512 WGs, 2/CU
constexpr int LDS_STRIDE = 136;     // bf16 elems/row
constexpr int BUFE = SAMP * LDS_STRIDE;   // 1088 elems per x/h buffer
constexpr int OS_STRIDE = 132;      // fp32 out-staging row stride
constexpr int OSB = SAMP * OS_STRIDE;     // 1056 floats per out buffer

__device__ __forceinline__ unsigned short f2bf(float f) {
  unsigned u = __float_as_uint(f);
  u += 0x7FFF + ((u >> 16) & 1);   // round-to-nearest-even
  return (unsigned short)(u >> 16);
}
__device__ __forceinline__ float bf2f(unsigned short s) {
  return __uint_as_float(((unsigned)s) << 16);
}
__device__ __forceinline__ float fast_sigmoid(float x) {
  float e = __builtin_amdgcn_exp2f(-1.44269504f * x);
  return __builtin_amdgcn_rcpf(1.0f + e);
}
__device__ __forceinline__ float fast_tanh(float x) {
  float e = __builtin_amdgcn_exp2f(2.88539008f * x);   // exp(2x)
  return 1.0f - 2.0f * __builtin_amdgcn_rcpf(1.0f + e);
}

// FULL drain + barrier, once per step. Empirical (rounds 0 vs 2/3): nt
// stores left undrained double HBM write traffic (312 -> 488 MB) and add
// fetch; draining vmcnt each step restores clean traffic. The drain stall
// is hidden by the SECOND workgroup on the CU (2 WG/CU), not by ILP.
__device__ __forceinline__ void wg_barrier_drain() {
  asm volatile("s_waitcnt vmcnt(0) lgkmcnt(0)" ::: "memory");
  __builtin_amdgcn_s_barrier();
  __builtin_amdgcn_sched_barrier(0);
}

// One WG owns 8 samples, runs all 114 steps. 8 waves; wave w owns gate
// columns {nt*128 + 16w .. +15}. Weights in VGPRs as bf16 B-fragments
// (128 VGPRs). MFMA A-tile rows 8..15 duplicate rows 0..7 (l15&7) —
// broadcast LDS reads, results masked off at write time (quad<2).
// xs/hs/os double-buffered -> one drained barrier per step.
__global__ __launch_bounds__(512, 4) void lstm_persistent(
    const float* __restrict__ img,   // [T][C][NPIX]
    const float* __restrict__ wih,   // [4H][C]
    const float* __restrict__ whh,   // [4H][H]
    const float* __restrict__ bih,
    const float* __restrict__ bhh,
    float* __restrict__ out)         // [NPIX][TT][H]
{
  __shared__ __align__(16) unsigned short xs[2 * BUFE];
  __shared__ __align__(16) unsigned short hs[2 * BUFE];
  __shared__ __align__(16) float os[2 * OSB];

  const int tid  = threadIdx.x;
  const int lane = tid & 63;
  const int w    = tid >> 6;      // wave 0..7
  const int l15  = lane & 15;
  const int quad = lane >> 4;     // 0..3
  // XCD swizzle (bijective, 512 WGs = 8 XCDs * 64): img cache lines
  // (128 B = 32 samples = 4 logical WGs) land on one XCD's L2.
  const int lb   = ((int)blockIdx.x & 7) * 64 + ((int)blockIdx.x >> 3);
  const int n0   = lb * SAMP;
  const int hid  = w * 16 + l15;  // hidden column this lane owns

  // ---- weight fragments (B-operand: lane holds B[k=quad*8+j][n=l15]) ----
  short8 fih[4][4], fhh[4][4];
  float bias[4];
  #pragma unroll
  for (int nt = 0; nt < 4; ++nt) {
    const int col = nt * 128 + hid;
    bias[nt] = bih[col] + bhh[col];
    #pragma unroll
    for (int kt = 0; kt < 4; ++kt) {
      const int k0 = kt * 32 + quad * 8;
      const float* pih = wih + col * C + k0;
      const float* phh = whh + col * C + k0;
      short8 a, b;
      #pragma unroll
      for (int j = 0; j < 8; ++j) {
        a[j] = (short)f2bf(pih[j]);
        b[j] = (short)f2bf(phh[j]);
      }
      fih[nt][kt] = a;
      fhh[nt][kt] = b;
    }
  }

  // zero h state in buffer 0
  for (int i = tid; i < BUFE; i += 512) hs[i] = 0;

  // fp32 cell state: lane owns (sample = (quad&1)*4 + r ... effectively
  // rows quad*4+r with rows 8..15 = duplicates of 0..7)
  float c[4] = {0.f, 0.f, 0.f, 0.f};

  // x staging: thread covers (nl = tid&7, channels cb, cb+1)
  const int nl = tid & 7;
  const int cb = (tid >> 3) * 2;
  const float* xbase = img + (size_t)cb * NPIX + n0 + nl;

  auto loadx = [&](int t) -> f32x2 {
    const float* p = xbase + (size_t)t * (C * NPIX);
    return (f32x2){p[0], p[NPIX]};
  };

  // stage x_0 into buf0
  {
    f32x2 q = loadx(0);
    ushort2 pk; pk.x = f2bf(q[0]); pk.y = f2bf(q[1]);
    *(ushort2*)&xs[nl * LDS_STRIDE + cb] = pk;
  }
  f32x2 qcur = loadx(1);   // in flight across step 0

  // A-frag element offset: rows 8..15 duplicate rows 0..7 (broadcast read)
  const int fro = (l15 & 7) * LDS_STRIDE + quad * 8;
  const bool wr = (quad < 2);   // this lane's acc rows are the valid ones

  // coalesced out-store mapping: wave w stores sample w's full 512-B row;
  // lane covers cols c2..c2+1 (f32x2, 64 lanes x 8 B = 512 B contiguous).
  const int ss = tid >> 6;          // sample 0..7 (== wave)
  const int c2 = (tid & 63) * 2;
  const size_t obs = (size_t)TT * H;
  float* osp = out + (size_t)(n0 + ss) * obs + c2;   // advances by H per step

  wg_barrier_drain();

  // one driven step: read bufs at so, write bufs at dso/oso;
  // consume qx into xs[dso] if wx
  auto step_drv = [&](int so, int dso, int oso, bool wx, f32x2 qx) {
    f32x4 acc[4];
    #pragma unroll
    for (int nt = 0; nt < 4; ++nt)
      acc[nt] = (f32x4){bias[nt], bias[nt], bias[nt], bias[nt]};
    #pragma unroll
    for (int kt = 0; kt < 4; ++kt) {
      short8 ax = *(const short8*)&xs[so + fro + kt * 32];
      short8 ah = *(const short8*)&hs[so + fro + kt * 32];
      #pragma unroll
      for (int nt = 0; nt < 4; ++nt) {
        acc[nt] = __builtin_amdgcn_mfma_f32_16x16x32_bf16(ax, fih[nt][kt], acc[nt], 0, 0, 0);
        acc[nt] = __builtin_amdgcn_mfma_f32_16x16x32_bf16(ah, fhh[nt][kt], acc[nt], 0, 0, 0);
      }
    }
    if (wx) {
      ushort2 pk; pk.x = f2bf(qx[0]); pk.y = f2bf(qx[1]);
      *(ushort2*)&xs[dso + nl * LDS_STRIDE + cb] = pk;
    }
    float hv[4];
    #pragma unroll
    for (int r = 0; r < 4; ++r) {
      float ig = fast_sigmoid(acc[0][r]);
      float fg = fast_sigmoid(acc[1][r]);
      float gg = fast_tanh(acc[2][r]);
      float og = fast_sigmoid(acc[3][r]);
      c[r] = fg * c[r] + ig * gg;
      hv[r] = og * fast_tanh(c[r]);
    }
    if (wr) {
      #pragma unroll
      for (int r = 0; r < 4; ++r) {
        hs[dso + (quad * 4 + r) * LDS_STRIDE + hid] = f2bf(hv[r]);
        os[oso + (quad * 4 + r) * OS_STRIDE + hid] = hv[r];
      }
    }
    wg_barrier_drain();
    // coalesced full-line out store (in flight until next step's drain)
    f32x2 v = *(const f32x2*)&os[oso + ss * OS_STRIDE + c2];
    __builtin_nontemporal_store(v, (f32x2*)osp);
    osp += H;
  };

  // one AR step: h feeds back as x; fih holds folded (Wih+Whh) by then
  auto step_ar = [&](int so, int dso, int oso) {
    f32x4 acc[4];
    #pragma unroll
    for (int nt = 0; nt < 4; ++nt)
      acc[nt] = (f32x4){bias[nt], bias[nt], bias[nt], bias[nt]};
    #pragma unroll
    for (int kt = 0; kt < 4; ++kt) {
      short8 ah = *(const short8*)&hs[so + fro + kt * 32];
      #pragma unroll
      for (int nt = 0; nt < 4; ++nt)
        acc[nt] = __builtin_amdgcn_mfma_f32_16x16x32_bf16(ah, fih[nt][kt], acc[nt], 0, 0, 0);
    }
    float hv[4];
    #pragma unroll
    for (int r = 0; r < 4; ++r) {
      float ig = fast_sigmoid(acc[0][r]);
      float fg = fast_sigmoid(acc[1][r]);
      float gg = fast_tanh(acc[2][r]);
      float og = fast_sigmoid(acc[3][r]);
      c[r] = fg * c[r] + ig * gg;
      hv[r] = og * fast_tanh(c[r]);
    }
    if (wr) {
      #pragma unroll
      for (int r = 0; r < 4; ++r) {
        hs[dso + (quad * 4 + r) * LDS_STRIDE + hid] = f2bf(hv[r]);
        os[oso + (quad * 4 + r) * OS_STRIDE + hid] = hv[r];
      }
    }
    wg_barrier_drain();
    f32x2 v = *(const f32x2*)&os[oso + ss * OS_STRIDE + c2];
    __builtin_nontemporal_store(v, (f32x2*)osp);
    osp += H;
  };

  // ---- driven phase: 60 steps, 2x unrolled, prefetch ~1.5 steps ahead.
  // stepA reads x_t from buf0, publishes x_{t+1}; stepB reads x_{t+1}
  // from buf1, publishes x_{t+2}. ----
  #pragma unroll 1
  for (int t = 0; t < T - 4; t += 2) {      // t = 0,2,..,54 -> steps 0..55
    f32x2 qA = loadx(t + 2);
    step_drv(0, BUFE, OSB, true, qcur);
    f32x2 qB = loadx(t + 3);
    step_drv(BUFE, 0, 0, true, qA);
    qcur = qB;
  }
  {                                          // steps 56,57
    f32x2 qA = loadx(58);
    step_drv(0, BUFE, OSB, true, qcur);      // reads x56, publishes x57
    f32x2 qB = loadx(59);
    step_drv(BUFE, 0, 0, true, qA);          // reads x57, publishes x58
    qcur = qB;
  }
  {                                          // steps 58,59
    step_drv(0, BUFE, OSB, true, qcur);      // reads x58, publishes x59
    step_drv(BUFE, 0, 0, false, qcur);       // reads x59; no x publish
  }

  // ---- fold W_sum = W_ih + W_hh into fih (registers only) ----
  #pragma unroll
  for (int nt = 0; nt < 4; ++nt)
    #pragma unroll
    for (int kt = 0; kt < 4; ++kt) {
      short8 a = fih[nt][kt], b = fhh[nt][kt];
      #pragma unroll
      for (int j = 0; j < 8; ++j)
        a[j] = (short)f2bf(bf2f((unsigned short)a[j]) + bf2f((unsigned short)b[j]));
      fih[nt][kt] = a;
    }

  // ---- AR phase: 54 steps, 2x unrolled; h state currently in buf0 ----
  #pragma unroll 1
  for (int t = 0; t < EXTRA; t += 2) {
    step_ar(0, BUFE, OSB);
    step_ar(BUFE, 0, 0);
  }
}

extern "C" void kernel_launch(void* const* d_in, const int* in_sizes, int n_in,
                              void* d_out, int out_size, void* d_ws, size_t ws_size,
                              hipStream_t stream) {
  (void)in_sizes; (void)n_in; (void)d_ws; (void)ws_size; (void)out_size;
  const float* img = (const float*)d_in[0];
  // d_in[1] = mask (unused by reference forward)
  const float* wih = (const float*)d_in[2];
  const float* whh = (const float*)d_in[3];
  const float* bih = (const float*)d_in[4];
  const float* bhh = (const float*)d_in[5];
  // d_in[6] = gp_affected_timesteps (static = 5, baked into EXTRA)
  float* out = (float*)d_out;

  lstm_persistent<<<NPIX / SAMP, 512, 0, stream>>>(img, wih, whh, bih, bhh, out);
}

// Round 5
// 532.854 us; speedup vs baseline: 2.8301x; 2.8301x over previous
//
#include <hip/hip_runtime.h>
#include <hip/hip_bf16.h>

typedef __attribute__((ext_vector_type(8))) short short8;
typedef __attribute__((ext_vector_type(4))) float f32x4;

constexpr int T    = 60;    // driven timesteps
constexpr int C    = 128;   // channels == hidden
constexpr int NPIX = 4096;  // samples
constexpr int H    = 128;
constexpr int GP   = 5;
constexpr int EXTRA = T - GP - 1;   // 54 autoregressive steps
constexpr int TT    = T + EXTRA;    // 114 total outputs
constexpr int LDS_STRIDE = 136;     // bf16 elems/row: 272 B, 16B-aligned
constexpr int BUFE = 16 * LDS_STRIDE;  // elems per LDS buffer (4352 B)
constexpr int OS_STRIDE = 132;      // fp32 out-staging row stride (breaks banks)
constexpr int OSB = 16 * OS_STRIDE; // floats per out-staging buffer

__device__ __forceinline__ unsigned short f2bf(float f) {
  unsigned u = __float_as_uint(f);
  u += 0x7FFF + ((u >> 16) & 1);   // round-to-nearest-even
  return (unsigned short)(u >> 16);
}
__device__ __forceinline__ float bf2f(unsigned short s) {
  return __uint_as_float(((unsigned)s) << 16);
}
__device__ __forceinline__ float fast_sigmoid(float x) {
  float e = __builtin_amdgcn_exp2f(-1.44269504f * x);
  return __builtin_amdgcn_rcpf(1.0f + e);
}
__device__ __forceinline__ float fast_tanh(float x) {
  float e = __builtin_amdgcn_exp2f(2.88539008f * x);   // exp(2x)
  return 1.0f - 2.0f * __builtin_amdgcn_rcpf(1.0f + e);
}

// Single FULLY-DRAINED barrier per step. Evidence (R0 vs R2/R3): nontemporal
// stores left undrained across many steps double HBM write traffic
// (312->488 MB) and add fetch; draining vmcnt each step keeps traffic clean.
// Everything drained here has had ~a full step in flight: x-loads were
// issued at step top, the out-store right after the PREVIOUS barrier.
__device__ __forceinline__ void wg_barrier_drain() {
  asm volatile("s_waitcnt vmcnt(0) lgkmcnt(0)" ::: "memory");
  __builtin_amdgcn_s_barrier();
  __builtin_amdgcn_sched_barrier(0);
}

// One WG owns 16 samples, runs all 114 steps. 8 waves; wave w owns gate
// columns {nt*128 + 16w .. +15}. Weights live in VGPRs as bf16 B-fragments
// (128 VGPRs -> REQUIRES __launch_bounds__(512,2); (512,4) caps VGPR at 64
// and spills the weights to scratch: R4 showed 2.78 GB fetch, 4x slower).
// xs/hs/os double-buffered -> ONE barrier per step. Output staged through
// fp32 LDS tile and stored as full 128-B lines (float4/lane, 512 B/row).
__global__ __launch_bounds__(512, 2) void lstm_persistent(
    const float* __restrict__ img,   // [T][C][NPIX]
    const float* __restrict__ wih,   // [4H][C]
    const float* __restrict__ whh,   // [4H][H]
    const float* __restrict__ bih,
    const float* __restrict__ bhh,
    float* __restrict__ out)         // [NPIX][TT][H]
{
  __shared__ __align__(16) unsigned short xs[2 * BUFE];
  __shared__ __align__(16) unsigned short hs[2 * BUFE];
  __shared__ __align__(16) float os[2 * OSB];

  const int tid  = threadIdx.x;
  const int lane = tid & 63;
  const int w    = tid >> 6;      // wave 0..7
  const int l15  = lane & 15;
  const int quad = lane >> 4;     // 0..3
  // XCD swizzle (bijective, 256 WGs = 8 XCDs * 32): logical neighbors
  // (which share img cache lines: 128 B = 32 samples = 2 WGs) land on the
  // same XCD's L2.
  const int lb   = ((int)blockIdx.x & 7) * 32 + ((int)blockIdx.x >> 3);
  const int n0   = lb * 16;
  const int hid  = w * 16 + l15;  // hidden column this lane owns

  // ---- weight fragments (B-operand: lane holds B[k=quad*8+j][n=l15]) ----
  short8 fih[4][4], fhh[4][4];
  float bias[4];
  #pragma unroll
  for (int nt = 0; nt < 4; ++nt) {
    const int col = nt * 128 + hid;
    bias[nt] = bih[col] + bhh[col];
    #pragma unroll
    for (int kt = 0; kt < 4; ++kt) {
      const int k0 = kt * 32 + quad * 8;
      const float* pih = wih + col * C + k0;
      const float* phh = whh + col * C + k0;
      short8 a, b;
      #pragma unroll
      for (int j = 0; j < 8; ++j) {
        a[j] = (short)f2bf(pih[j]);
        b[j] = (short)f2bf(phh[j]);
      }
      fih[nt][kt] = a;
      fhh[nt][kt] = b;
    }
  }

  // zero h state in buffer 0
  for (int i = tid; i < BUFE; i += 512) hs[i] = 0;

  // fp32 cell state: lane owns (sample = quad*4 + r, hid)
  float c[4] = {0.f, 0.f, 0.f, 0.f};

  // x staging: thread covers (nl = tid&15, channels cb..cb+3)
  const int nl = tid & 15;
  const int cb = (tid >> 4) * 4;
  const float* xbase = img + (size_t)cb * NPIX + n0 + nl;

  auto loadx = [&](int t) -> f32x4 {
    const float* p = xbase + (size_t)t * (C * NPIX);
    return (f32x4){p[0], p[NPIX], p[2 * NPIX], p[3 * NPIX]};
  };

  // stage x_0 into buf0
  {
    f32x4 q = loadx(0);
    ushort4 pk;
    pk.x = f2bf(q[0]); pk.y = f2bf(q[1]); pk.z = f2bf(q[2]); pk.w = f2bf(q[3]);
    *(ushort4*)&xs[nl * LDS_STRIDE + cb] = pk;
  }
  f32x4 qcur = loadx(1);   // in flight across step 0
  wg_barrier_drain();

  const int fro = l15 * LDS_STRIDE + quad * 8;  // A-frag element offset

  // coalesced out-store mapping: thread covers (sample ss, cols c4..c4+3);
  // 32 consecutive lanes write 512 B contiguous = 4 FULL 128-B lines.
  const int ss = tid >> 5;          // sample 0..15
  const int c4 = (tid & 31) * 4;    // hid column 0,4,..,124
  const size_t obs = (size_t)TT * H;
  float* osp = out + (size_t)(n0 + ss) * obs + c4;   // advances by H per step

  // one driven step: read bufs at so, write bufs at dso (and os at oso);
  // consume qx into xs[dso] if wx
  auto step_drv = [&](int so, int dso, int oso, bool wx, f32x4 qx) {
    f32x4 acc[4];
    #pragma unroll
    for (int nt = 0; nt < 4; ++nt)
      acc[nt] = (f32x4){bias[nt], bias[nt], bias[nt], bias[nt]};
    #pragma unroll
    for (int kt = 0; kt < 4; ++kt) {
      short8 ax = *(const short8*)&xs[so + fro + kt * 32];
      short8 ah = *(const short8*)&hs[so + fro + kt * 32];
      #pragma unroll
      for (int nt = 0; nt < 4; ++nt) {
        acc[nt] = __builtin_amdgcn_mfma_f32_16x16x32_bf16(ax, fih[nt][kt], acc[nt], 0, 0, 0);
        acc[nt] = __builtin_amdgcn_mfma_f32_16x16x32_bf16(ah, fhh[nt][kt], acc[nt], 0, 0, 0);
      }
    }
    // publish next x tile (qx load completed by the drain at the end of the
    // step it was issued in -> pack waits ~0 here)
    if (wx) {
      ushort4 pk;
      pk.x = f2bf(qx[0]); pk.y = f2bf(qx[1]); pk.z = f2bf(qx[2]); pk.w = f2bf(qx[3]);
      *(ushort4*)&xs[dso + nl * LDS_STRIDE + cb] = pk;
    }
    float hv[4];
    #pragma unroll
    for (int r = 0; r < 4; ++r) {
      float ig = fast_sigmoid(acc[0][r]);
      float fg = fast_sigmoid(acc[1][r]);
      float gg = fast_tanh(acc[2][r]);
      float og = fast_sigmoid(acc[3][r]);
      c[r] = fg * c[r] + ig * gg;
      hv[r] = og * fast_tanh(c[r]);
    }
    #pragma unroll
    for (int r = 0; r < 4; ++r) {
      hs[dso + (quad * 4 + r) * LDS_STRIDE + hid] = f2bf(hv[r]);
      os[oso + (quad * 4 + r) * OS_STRIDE + hid] = hv[r];
    }
    wg_barrier_drain();
    // coalesced full-line out store: fires now, drains at the NEXT step's
    // barrier (a full step of cover)
    {
      f32x4 v = *(const f32x4*)&os[oso + ss * OS_STRIDE + c4];
      __builtin_nontemporal_store(v, (f32x4*)osp);
      osp += H;
    }
  };

  // one AR step: h feeds back as x; fih holds folded (Wih+Whh) by then
  auto step_ar = [&](int so, int dso, int oso) {
    f32x4 acc[4];
    #pragma unroll
    for (int nt = 0; nt < 4; ++nt)
      acc[nt] = (f32x4){bias[nt], bias[nt], bias[nt], bias[nt]};
    #pragma unroll
    for (int kt = 0; kt < 4; ++kt) {
      short8 ah = *(const short8*)&hs[so + fro + kt * 32];
      #pragma unroll
      for (int nt = 0; nt < 4; ++nt)
        acc[nt] = __builtin_amdgcn_mfma_f32_16x16x32_bf16(ah, fih[nt][kt], acc[nt], 0, 0, 0);
    }
    float hv[4];
    #pragma unroll
    for (int r = 0; r < 4; ++r) {
      float ig = fast_sigmoid(acc[0][r]);
      float fg = fast_sigmoid(acc[1][r]);
      float gg = fast_tanh(acc[2][r]);
      float og = fast_sigmoid(acc[3][r]);
      c[r] = fg * c[r] + ig * gg;
      hv[r] = og * fast_tanh(c[r]);
    }
    #pragma unroll
    for (int r = 0; r < 4; ++r) {
      hs[dso + (quad * 4 + r) * LDS_STRIDE + hid] = f2bf(hv[r]);
      os[oso + (quad * 4 + r) * OS_STRIDE + hid] = hv[r];
    }
    wg_barrier_drain();
    {
      f32x4 v = *(const f32x4*)&os[oso + ss * OS_STRIDE + c4];
      __builtin_nontemporal_store(v, (f32x4*)osp);
      osp += H;
    }
  };

  // ---- driven phase: 60 steps, 2x unrolled. stepA reads x_t from buf0,
  // publishes x_{t+1}; stepB reads x_{t+1} from buf1, publishes x_{t+2}. ----
  #pragma unroll 1
  for (int t = 0; t < T - 4; t += 2) {      // t = 0,2,..,54 -> steps 0..55
    f32x4 qA = loadx(t + 2);
    step_drv(0, BUFE, OSB, true, qcur);
    f32x4 qB = loadx(t + 3);
    step_drv(BUFE, 0, 0, true, qA);
    qcur = qB;
  }
  {                                          // steps 56,57
    f32x4 qA = loadx(58);
    step_drv(0, BUFE, OSB, true, qcur);      // reads x56, publishes x57
    f32x4 qB = loadx(59);
    step_drv(BUFE, 0, 0, true, qA);          // reads x57, publishes x58
    qcur = qB;
  }
  {                                          // steps 58,59
    step_drv(0, BUFE, OSB, true, qcur);      // reads x58, publishes x59
    step_drv(BUFE, 0, 0, false, qcur);       // reads x59; no x publish
  }

  // ---- fold W_sum = W_ih + W_hh into fih (registers only, no sync needed) ----
  #pragma unroll
  for (int nt = 0; nt < 4; ++nt)
    #pragma unroll
    for (int kt = 0; kt < 4; ++kt) {
      short8 a = fih[nt][kt], b = fhh[nt][kt];
      #pragma unroll
      for (int j = 0; j < 8; ++j)
        a[j] = (short)f2bf(bf2f((unsigned short)a[j]) + bf2f((unsigned short)b[j]));
      fih[nt][kt] = a;
    }

  // ---- AR phase: 54 steps, 2x unrolled; h state currently in buf0 ----
  #pragma unroll 1
  for (int t = 0; t < EXTRA; t += 2) {
    step_ar(0, BUFE, OSB);
    step_ar(BUFE, 0, 0);
  }
}

extern "C" void kernel_launch(void* const* d_in, const int* in_sizes, int n_in,
                              void* d_out, int out_size, void* d_ws, size_t ws_size,
                              hipStream_t stream) {
  (void)in_sizes; (void)n_in; (void)d_ws; (void)ws_size; (void)out_size;
  const float* img = (const float*)d_in[0];
  // d_in[1] = mask (unused by reference forward)
  const float* wih = (const float*)d_in[2];
  const float* whh = (const float*)d_in[3];
  const float* bih = (const float*)d_in[4];
  const float* bhh = (const float*)d_in[5];
  // d_in[6] = gp_affected_timesteps (static = 5, baked into EXTRA)
  float* out = (float*)d_out;

  lstm_persistent<<<NPIX / 16, 512, 0, stream>>>(img, wih, whh, bih, bhh, out);
}